// Round 4
// baseline (198.669 us; speedup 1.0000x reference)
//
#include <hip/hip_runtime.h>
#include <hip/hip_bf16.h>

#define NB 4
#define CH 256
#define HH 64
#define WW 64
#define NPIX 4096      // HH*WW
#define OH 62
#define NPATCH 3844    // 62*62
#define KDIM 256       // == CH
#define EPSN 1e-12f
#define VROW 68        // V row stride (floats): 16B-aligned rows
#define SEG 8          // diagonal segment length (pairs per block)
#define PST 68         // k_prep stage row stride (shorts): 8B-aligned rows

typedef __attribute__((ext_vector_type(8))) short short8;
typedef __attribute__((ext_vector_type(4))) float f32x4;

__device__ __forceinline__ float bf16_to_f32(unsigned short u) {
    return __uint_as_float((unsigned)u << 16);
}
__device__ __forceinline__ unsigned short f32_to_bf16(float f) {
    __hip_bfloat16 h = __float2bfloat16(f);
    return *(unsigned short*)&h;
}

// ---- K1 (fused prep): read inputs ONCE; per-pixel ss + inv-norm; normalized bf16
// ---- transpose (C,pix)->(pix,C). Also zero-inits d_out + keys.
__global__ __launch_bounds__(256) void k_prep(const float* __restrict__ pred,
                                              const float* __restrict__ tgt,
                                              __hip_bfloat16* __restrict__ Xn,
                                              __hip_bfloat16* __restrict__ Tn,
                                              float* __restrict__ ssP, float* __restrict__ invP,
                                              float* __restrict__ ssT, float* __restrict__ invT,
                                              unsigned long long* __restrict__ keys,
                                              float* __restrict__ out) {
    const int bz = blockIdx.y;            // 0..7
    const int b = bz >> 1, which = bz & 1;
    const float* src = (which ? tgt : pred) + (size_t)b * CH * NPIX;
    unsigned short* dst = (unsigned short*)((which ? Tn : Xn) + (size_t)b * NPIX * CH);
    float* ss_g  = (which ? ssT  : ssP)  + b * NPIX;
    float* inv_g = (which ? invT : invP) + b * NPIX;
    const int pix0 = blockIdx.x * 64;
    const int t = threadIdx.x, lane = t & 63, wv = t >> 6;

    int gid = (bz * 64 + blockIdx.x) * 256 + t;
    if (gid < NB * NPATCH) keys[gid] = 0ull;
    if (gid == 0) out[0] = 0.f;

    __shared__ unsigned short stage[CH][PST];  // 34816 B
    __shared__ float partial[16][68];          // 4352 B (+pad: 2-way reads)
    __shared__ float inv_s[64];

    // load: thread (cb = t>>4, ch = t&15) covers c = cb*16+r (r<16), pixels ch*4..+3
    const int cb = t >> 4, chk = t & 15;
    float ss0 = 0.f, ss1 = 0.f, ss2 = 0.f, ss3 = 0.f;
#pragma unroll
    for (int r = 0; r < 16; ++r) {
        int c = cb * 16 + r;
        float4 v = *(const float4*)&src[(size_t)c * NPIX + pix0 + chk * 4];
        ss0 += v.x * v.x; ss1 += v.y * v.y; ss2 += v.z * v.z; ss3 += v.w * v.w;
        ushort4 sv;
        sv.x = f32_to_bf16(v.x); sv.y = f32_to_bf16(v.y);
        sv.z = f32_to_bf16(v.z); sv.w = f32_to_bf16(v.w);
        *(ushort4*)&stage[c][chk * 4] = sv;
    }
    float4 pv; pv.x = ss0; pv.y = ss1; pv.z = ss2; pv.w = ss3;
    *(float4*)&partial[cb][chk * 4] = pv;
    __syncthreads();
    if (t < 64) {
        float ss = 0.f;
#pragma unroll
        for (int r = 0; r < 16; ++r) ss += partial[r][t];
        float inv = 1.f / fmaxf(sqrtf(ss), EPSN);
        ss_g[pix0 + t] = ss;
        inv_g[pix0 + t] = inv;
        inv_s[t] = inv;
    }
    __syncthreads();
    // write: pixel p (16/wave), lane = c within 64-chunk; 2-way-free LDS reads
    for (int p = wv; p < 64; p += 4) {
        float iv = inv_s[p];
#pragma unroll
        for (int cc = 0; cc < 4; ++cc) {
            int c = cc * 64 + lane;
            float v = bf16_to_f32(stage[c][p]) * iv;
            dst[(size_t)(pix0 + p) * CH + c] = f32_to_bf16(v);
        }
    }
}

// ------- K2: D = Xn * Tn^T (4096x4096, K=256, bf16 MFMA, bf16 OUTPUT).
// R4 reshape (per-CU model: LDS-port ~30us was the binding pipe, HBM 27, MFMA 16):
//  * 128x256 block, 4 waves each 128x64 -> ds_read ratio 0.375 (12 b128 / 32 mfma
//    = LDS parity with MFMA pipe), BK=32, dbuf 48 KB -> 2-3 blocks/CU (fixes R2's
//    1-blk occupancy collapse).
//  * counted vmcnt(6), prefetch distance 2 (12 loads in flight), 8 K-steps.
//  * R2-PROVEN swapped mfma(b,a) + uint2 register epilogue: zero LDS epilogue.
//  * slot-XOR swizzle (kq ^ (row&3)) staged via pre-swizzled global source.
//  * split into 2 z-dispatches for rocprof visibility; XCD-bijective swizzle.
__device__ __forceinline__ void gload_lds16(const void* g, void* l) {
    __builtin_amdgcn_global_load_lds(
        (const __attribute__((address_space(1))) void*)g,
        (__attribute__((address_space(3))) void*)l, 16, 0, 0);
}

__global__ __launch_bounds__(256, 2) void k_gemm(const __hip_bfloat16* __restrict__ A,
                                                 const __hip_bfloat16* __restrict__ Bm,
                                                 unsigned short* __restrict__ Dout,
                                                 int zbase) {
    // 48 KB arena (shorts): As0 [0,4096) As1 [4096,8192)
    //                       Bs0 [8192,16384) Bs1 [16384,24576)
    __shared__ __align__(16) short smem[24576];
#define ASOFF(buf) ((buf) * 4096)
#define BSOFF(buf) (8192 + (buf) * 8192)

    const int t = threadIdx.x;
    const int lane = t & 63, wv = t >> 6;          // 4 waves
    const int wn = wv;                             // wave's 64-col slice of N=256

    // XCD-bijective swizzle over 1024 blocks (nwg%8==0)
    const int bid = ((blockIdx.z << 5) + blockIdx.y) * 16 + blockIdx.x;  // 0..1023
    const int swz = ((bid & 7) << 7) + (bid >> 3);
    const int z = zbase + (swz >> 9), by = (swz >> 4) & 31, bx = swz & 15;

    const int row0 = by * 128, col0 = bx * 256;
    const short* Ag = (const short*)A + (size_t)z * NPIX * CH;
    const short* Bg = (const short*)Bm + (size_t)z * NPIX * CH;
    unsigned short* D = Dout + (size_t)z * NPIX * NPIX;

    const int srow = t >> 2;                        // 0..63 (row within 64-row chunk)
    const int kce  = ((t & 3) ^ (srow & 3)) * 8;    // pre-swizzled k-chunk (shorts)

    f32x4 acc[8][4] = {};

    // stage one BK=32 slab: A 128 rows (2 chunks) + B 256 rows (4 chunks); rows
    // are 64 B -> one gload instr covers 16 rows; 6 gload instrs per thread.
#define STAGE_K(buf, k0)                                                                   \
    do {                                                                                   \
        _Pragma("unroll")                                                                  \
        for (int rr_ = 0; rr_ < 2; ++rr_)                                                  \
            gload_lds16(Ag + (size_t)(row0 + rr_ * 64 + srow) * KDIM + (k0) + kce,         \
                        &smem[ASOFF(buf) + rr_ * 2048 + wv * 512]);                        \
        _Pragma("unroll")                                                                  \
        for (int cc_ = 0; cc_ < 4; ++cc_)                                                  \
            gload_lds16(Bg + (size_t)(col0 + cc_ * 64 + srow) * KDIM + (k0) + kce,         \
                        &smem[BSOFF(buf) + cc_ * 2048 + wv * 512]);                        \
    } while (0)

    const int rsel = lane & 15, kq = lane >> 4;
    const int pk = (kq ^ (rsel & 3)) * 8;          // swizzled slot offset (shorts)

    // SWAPPED operands (R2-proven): acc[mi][ni] = mfma(b,a) -> lane&15 = A-row in
    // frag, (lane>>4)*4+reg = 4 consecutive B-cols.
#define CONSUME(buf)                                                                       \
    do {                                                                                   \
        short8 a_[8], b_[4];                                                               \
        _Pragma("unroll")                                                                  \
        for (int mi = 0; mi < 8; ++mi)                                                     \
            a_[mi] = *(const short8*)&smem[ASOFF(buf) + (mi * 16 + rsel) * 32 + pk];       \
        _Pragma("unroll")                                                                  \
        for (int ni = 0; ni < 4; ++ni)                                                     \
            b_[ni] = *(const short8*)&smem[BSOFF(buf) + (wn * 64 + ni * 16 + rsel) * 32 + pk]; \
        _Pragma("unroll")                                                                  \
        for (int mi = 0; mi < 8; ++mi)                                                     \
            _Pragma("unroll")                                                              \
            for (int ni = 0; ni < 4; ++ni)                                                 \
                acc[mi][ni] = __builtin_amdgcn_mfma_f32_16x16x32_bf16(b_[ni], a_[mi],      \
                                                                      acc[mi][ni], 0, 0, 0); \
    } while (0)

#define KITER(it, VMC)                                              \
    do {                                                            \
        asm volatile("s_waitcnt vmcnt(" #VMC ")" ::: "memory");     \
        __builtin_amdgcn_sched_barrier(0);                          \
        __builtin_amdgcn_s_barrier();                               \
        __builtin_amdgcn_sched_barrier(0);                          \
        CONSUME((it) & 1);                                          \
        asm volatile("s_waitcnt lgkmcnt(0)" ::: "memory");          \
        __builtin_amdgcn_sched_barrier(0);                          \
        __builtin_amdgcn_s_barrier();                               \
        __builtin_amdgcn_sched_barrier(0);                          \
        if ((it) < 6) STAGE_K((it) & 1, ((it) + 2) * 32);           \
    } while (0)

    STAGE_K(0, 0);
    STAGE_K(1, 32);        // 12 loads in flight
    KITER(0, 6);
    KITER(1, 6);
    KITER(2, 6);
    KITER(3, 6);
    KITER(4, 6);
    KITER(5, 6);
    KITER(6, 6);
    KITER(7, 0);
#undef KITER
#undef CONSUME
#undef STAGE_K

    // ---- epilogue: direct register stores, 8B contiguous per lane ----
    const int r16 = lane & 15, c4 = (lane >> 4) * 4;
#pragma unroll
    for (int mi = 0; mi < 8; ++mi) {
        const size_t rowoff = (size_t)(row0 + mi * 16 + r16) * NPIX;
#pragma unroll
        for (int ni = 0; ni < 4; ++ni) {
            uint2 u;
            u.x = (unsigned)f32_to_bf16(acc[mi][ni][0]) |
                  ((unsigned)f32_to_bf16(acc[mi][ni][1]) << 16);
            u.y = (unsigned)f32_to_bf16(acc[mi][ni][2]) |
                  ((unsigned)f32_to_bf16(acc[mi][ni][3]) << 16);
            *(uint2*)&D[rowoff + col0 + wn * 64 + ni * 16 + c4] = u;
        }
    }
#undef ASOFF
#undef BSOFF
}

__device__ __forceinline__ void load_tile16(const unsigned short* __restrict__ D,
                                            int row, int col, float* f) {
    const unsigned short* rp = D + (size_t)row * NPIX + col;
    uint4 u0 = *(const uint4*)rp;
    uint4 u1 = *(const uint4*)(rp + 8);
    const unsigned* w0 = (const unsigned*)&u0;
    const unsigned* w1 = (const unsigned*)&u1;
#pragma unroll
    for (int w = 0; w < 4; ++w) {
        f[2 * w]         = bf16_to_f32((unsigned short)w0[w]);
        f[2 * w + 1]     = bf16_to_f32((unsigned short)(w0[w] >> 16));
        f[8 + 2 * w]     = bf16_to_f32((unsigned short)w1[w]);
        f[8 + 2 * w + 1] = bf16_to_f32((unsigned short)(w1[w] >> 16));
    }
}

// ---- K3 (k_score): rolling diagonal segments, SEG=8.
// R4: DPP score phase. qc = lane; each lane reads ONE V row (5 b128, r[20]);
// rows qc+1 / qc+2 come from lanes qc+1 / qc+2 via v_mov_dpp row_shl:1/2 (VALU,
// not LDS port). Lanes crossing the 16-lane DPP row ((lane&15)>=14) fall back to
// direct LDS row reads. Sum order r + row1 + row2 == old r0 + r1 + r2 (bitwise).
// LDS reads/thread-step: 14 b128 -> 5 (+0.9 avg fallback).
__global__ __launch_bounds__(256) void k_score(const unsigned short* __restrict__ Dbase,
                                               unsigned long long* __restrict__ keys) {
    const int z = blockIdx.z;
    const unsigned short* D = Dbase + (size_t)z * NPIX * NPIX;
    const int t = threadIdx.x;

    const int d = (int)blockIdx.x - 61;            // diagonal qr-pr in [-61, 61]
    const int adg = d < 0 ? -d : d;
    const int len = 62 - adg;
    const int s0 = blockIdx.y * SEG;
    if (s0 >= len) return;
    const int steps = min(SEG, len - s0);
    const int qr0 = (d > 0 ? d : 0) + s0;
    const int pr0 = qr0 - d;

    __shared__ __align__(16) float V[64 * VROW];   // 17408 B -> 9 blocks/CU

    const int a = t >> 2, b0 = (t & 3) * 16;
    const int g = t >> 6, qc = t & 63;             // qc = lane within wave
    const int l15 = qc & 15;
    const int pc0 = g * 16;
    const int kmax = (g == 3) ? 14 : 16;

    float A[16], B[16], C[16];
    load_tile16(D, (qr0 + 0) * 64 + a, (pr0 + 0) * 64 + b0, A);
    load_tile16(D, (qr0 + 1) * 64 + a, (pr0 + 1) * 64 + b0, B);

    for (int k = 0; k < steps; ++k) {
        load_tile16(D, (qr0 + k + 2) * 64 + a, (pr0 + k + 2) * 64 + b0, C);
        float v[16];
#pragma unroll
        for (int e = 0; e < 16; ++e) v[e] = A[e] + B[e] + C[e];
        if (k) __syncthreads();                    // step k-1 score reads done
#pragma unroll
        for (int e = 0; e < 16; e += 4)
            *(f32x4*)&V[a * VROW + b0 + e] = *(const f32x4*)&v[e];
        __syncthreads();

        // own row qc (rows 0..63 all exist; qc>=62 lanes are DPP donors only)
        float r[20];
#pragma unroll
        for (int e = 0; e < 20; e += 4)
            *(f32x4*)&r[e] = *(const f32x4*)&V[qc * VROW + pc0 + e];
        // DPP-row-boundary fallbacks (12 of 64 lanes)
        float rB[20], rC[20];
        if (l15 >= 14) {
            int rowC = qc + 2 > 63 ? 63 : qc + 2;
#pragma unroll
            for (int e = 0; e < 20; e += 4)
                *(f32x4*)&rC[e] = *(const f32x4*)&V[rowC * VROW + pc0 + e];
            if (l15 == 15) {
                int rowB = qc + 1 > 63 ? 63 : qc + 1;
#pragma unroll
                for (int e = 0; e < 20; e += 4)
                    *(f32x4*)&rB[e] = *(const f32x4*)&V[rowB * VROW + pc0 + e];
            }
        }

        float best = -1e30f; int bpc = 0;
#pragma unroll
        for (int kk = 0; kk < 16; ++kk) {
            // row_shl:1 (0x101): lane i <- lane i+1 ; row_shl:2 (0x102): <- i+2
            float v1 = __uint_as_float((unsigned)__builtin_amdgcn_mov_dpp(
                           (int)__float_as_uint(r[kk + 1]), 0x101, 0xf, 0xf, true));
            float v2 = __uint_as_float((unsigned)__builtin_amdgcn_mov_dpp(
                           (int)__float_as_uint(r[kk + 2]), 0x102, 0xf, 0xf, true));
            if (l15 == 15) v1 = rB[kk + 1];
            if (l15 >= 14) v2 = rC[kk + 2];
            float s = r[kk] + v1 + v2;
            if (kk < kmax && s > best) { best = s; bpc = pc0 + kk; }
        }
        if (qc < OH) {
            unsigned u = __float_as_uint(best);
            u = (best >= 0.f) ? (u | 0x80000000u) : ~u;
            unsigned long long key = ((unsigned long long)u << 12)
                                   | (unsigned)((63 - (pr0 + k)) << 6)
                                   | (unsigned)(63 - bpc);
            atomicMax(&keys[(size_t)z * NPATCH + (qr0 + k) * OH + qc], key);
        }
#pragma unroll
        for (int e = 0; e < 16; ++e) { A[e] = B[e]; B[e] = C[e]; }
    }
}

// -------- K4 (k_loss): decode keys -> match; loss via norm expansion --------
__global__ void k_loss(const unsigned short* __restrict__ Dbase,
                       const unsigned long long* __restrict__ keys,
                       const float* __restrict__ ssPb, const float* __restrict__ invPb,
                       const float* __restrict__ ssTb, const float* __restrict__ invTb,
                       float* __restrict__ out) {
    const int z = blockIdx.y;
    const unsigned short* D = Dbase + (size_t)z * NPIX * NPIX;
    const float* ssP  = ssPb  + z * NPIX;
    const float* invP = invPb + z * NPIX;
    const float* ssT  = ssTb  + z * NPIX;
    const float* invT = invTb + z * NPIX;
    int q = blockIdx.x * 256 + threadIdx.x;
    float acc = 0.f;
    if (q < NPATCH) {
        int qr = q / OH, qc = q - qr * OH;
        int qpix = qr * WW + qc;
        unsigned long long key = keys[(size_t)z * NPATCH + q];
        int mpr = 63 - (int)((key >> 6) & 63);
        int mpc = 63 - (int)(key & 63);
        int mpix = mpr * WW + mpc;
#pragma unroll
        for (int i = 0; i < 3; ++i)
#pragma unroll
            for (int j = 0; j < 3; ++j) {
                int off = i * WW + j;
                int y = qpix + off, x = mpix + off;
                float Dv = bf16_to_f32(D[(size_t)y * NPIX + x]);
                float nP = ssP[y] * invP[y];       // = ||p_y||
                float nT = ssT[x] * invT[x];
                acc += ssP[y] + ssT[x] - 2.f * Dv * nP * nT;
            }
    }
#pragma unroll
    for (int s = 32; s > 0; s >>= 1) acc += __shfl_down(acc, s, 64);
    if ((threadIdx.x & 63) == 0)
        atomicAdd(out, acc * (1.f / 35426304.f));  // / (4*3844*2304)
}

// ---------------------------------- launch ----------------------------------
extern "C" void kernel_launch(void* const* d_in, const int* in_sizes, int n_in,
                              void* d_out, int out_size, void* d_ws, size_t ws_size,
                              hipStream_t stream) {
    const float* pred = (const float*)d_in[0];
    const float* tgt  = (const float*)d_in[1];
    char* ws = (char*)d_ws;
    // ws layout (bytes), ws_size = 256 MiB:
    // D(bf16, 4 batches) 128MB | Xn 8MB | Tn 8MB | norms 4x64KB | keys 123KB
    unsigned short*     Dws  = (unsigned short*)(ws);
    __hip_bfloat16*     Xn   = (__hip_bfloat16*)(ws + 134217728);
    __hip_bfloat16*     Tn   = (__hip_bfloat16*)(ws + 142606336);
    float*              ssP  = (float*)(ws + 150994944);
    float*              invP = (float*)(ws + 151060480);
    float*              ssT  = (float*)(ws + 151126016);
    float*              invT = (float*)(ws + 151191552);
    unsigned long long* keys = (unsigned long long*)(ws + 151257088);

    k_prep<<<dim3(64, 8), 256, 0, stream>>>(pred, tgt, Xn, Tn, ssP, invP, ssT, invT,
                                            keys, (float*)d_out);
    k_gemm<<<dim3(16, 32, 2), 256, 0, stream>>>(Xn, Tn, Dws, 0);
    k_gemm<<<dim3(16, 32, 2), 256, 0, stream>>>(Xn, Tn, Dws, 2);
    k_score<<<dim3(123, 8, 4), 256, 0, stream>>>(Dws, keys);
    k_loss<<<dim3(16, 4), 256, 0, stream>>>(Dws, keys, ssP, invP, ssT, invT,
                                            (float*)d_out);
}

// Round 5
// 183.810 us; speedup vs baseline: 1.0808x; 1.0808x over previous
//
#include <hip/hip_runtime.h>
#include <hip/hip_bf16.h>

#define NB 4
#define CH 256
#define HH 64
#define WW 64
#define NPIX 4096      // HH*WW
#define OH 62
#define NPATCH 3844    // 62*62
#define KDIM 256       // == CH
#define EPSN 1e-12f
#define VROW 68        // V row stride (floats): 16B-aligned rows
#define SEG 8          // diagonal segment length (pairs per block)
#define PST 68         // k_prep stage row stride (shorts): 8B-aligned rows

typedef __attribute__((ext_vector_type(8))) short short8;
typedef __attribute__((ext_vector_type(4))) float f32x4;

__device__ __forceinline__ float bf16_to_f32(unsigned short u) {
    return __uint_as_float((unsigned)u << 16);
}
__device__ __forceinline__ unsigned short f32_to_bf16(float f) {
    __hip_bfloat16 h = __float2bfloat16(f);
    return *(unsigned short*)&h;
}

// ---- K1 (fused prep): read inputs ONCE; per-pixel ss + inv-norm; normalized bf16
// ---- transpose (C,pix)->(pix,C). Also zero-inits d_out + keys.
__global__ __launch_bounds__(256) void k_prep(const float* __restrict__ pred,
                                              const float* __restrict__ tgt,
                                              __hip_bfloat16* __restrict__ Xn,
                                              __hip_bfloat16* __restrict__ Tn,
                                              float* __restrict__ ssP, float* __restrict__ invP,
                                              float* __restrict__ ssT, float* __restrict__ invT,
                                              unsigned long long* __restrict__ keys,
                                              float* __restrict__ out) {
    const int bz = blockIdx.y;            // 0..7
    const int b = bz >> 1, which = bz & 1;
    const float* src = (which ? tgt : pred) + (size_t)b * CH * NPIX;
    unsigned short* dst = (unsigned short*)((which ? Tn : Xn) + (size_t)b * NPIX * CH);
    float* ss_g  = (which ? ssT  : ssP)  + b * NPIX;
    float* inv_g = (which ? invT : invP) + b * NPIX;
    const int pix0 = blockIdx.x * 64;
    const int t = threadIdx.x, lane = t & 63, wv = t >> 6;

    int gid = (bz * 64 + blockIdx.x) * 256 + t;
    if (gid < NB * NPATCH) keys[gid] = 0ull;
    if (gid == 0) out[0] = 0.f;

    __shared__ unsigned short stage[CH][PST];  // 34816 B
    __shared__ float partial[16][68];          // 4352 B (+pad: 2-way reads)
    __shared__ float inv_s[64];

    // load: thread (cb = t>>4, ch = t&15) covers c = cb*16+r (r<16), pixels ch*4..+3
    const int cb = t >> 4, chk = t & 15;
    float ss0 = 0.f, ss1 = 0.f, ss2 = 0.f, ss3 = 0.f;
#pragma unroll
    for (int r = 0; r < 16; ++r) {
        int c = cb * 16 + r;
        float4 v = *(const float4*)&src[(size_t)c * NPIX + pix0 + chk * 4];
        ss0 += v.x * v.x; ss1 += v.y * v.y; ss2 += v.z * v.z; ss3 += v.w * v.w;
        ushort4 sv;
        sv.x = f32_to_bf16(v.x); sv.y = f32_to_bf16(v.y);
        sv.z = f32_to_bf16(v.z); sv.w = f32_to_bf16(v.w);
        *(ushort4*)&stage[c][chk * 4] = sv;
    }
    float4 pv; pv.x = ss0; pv.y = ss1; pv.z = ss2; pv.w = ss3;
    *(float4*)&partial[cb][chk * 4] = pv;
    __syncthreads();
    if (t < 64) {
        float ss = 0.f;
#pragma unroll
        for (int r = 0; r < 16; ++r) ss += partial[r][t];
        float inv = 1.f / fmaxf(sqrtf(ss), EPSN);
        ss_g[pix0 + t] = ss;
        inv_g[pix0 + t] = inv;
        inv_s[t] = inv;
    }
    __syncthreads();
    // write: pixel p (16/wave), lane = c within 64-chunk; 2-way-free LDS reads
    for (int p = wv; p < 64; p += 4) {
        float iv = inv_s[p];
#pragma unroll
        for (int cc = 0; cc < 4; ++cc) {
            int c = cc * 64 + lane;
            float v = bf16_to_f32(stage[c][p]) * iv;
            dst[(size_t)(pix0 + p) * CH + c] = f32_to_bf16(v);
        }
    }
}

// ------- K2: D = Xn * Tn^T (4096x4096, K=256, bf16 MFMA, bf16 OUTPUT).
// R5: LOCKED to the R1/R3-proven config (57.3 us combined, three independent
// measurements; R2/R4 reshapes both failed to beat it). Split into two
// z-dispatches (zbase = 0, 2) for rocprof visibility of k_score.
__device__ __forceinline__ void gload_lds16(const void* g, void* l) {
    __builtin_amdgcn_global_load_lds(
        (const __attribute__((address_space(1))) void*)g,
        (__attribute__((address_space(3))) void*)l, 16, 0, 0);
}

__global__ __launch_bounds__(256, 2) void k_gemm(const __hip_bfloat16* __restrict__ A,
                                                 const __hip_bfloat16* __restrict__ Bm,
                                                 unsigned short* __restrict__ Dout,
                                                 int zbase) {
    // one 64 KB arena: As buf0 [0,8192), As buf1 [8192,16384),
    //                  Bs buf0 [16384,24576), Bs buf1 [24576,32768) (shorts)
    __shared__ __align__(16) short smem[32768];
#define ASOFF(buf) ((buf) * 8192)
#define BSOFF(buf) (16384 + (buf) * 8192)

    const int t = threadIdx.x;
    const int lane = t & 63, wv = t >> 6;          // 4 waves
    const int wm = wv >> 1, wn = wv & 1;           // 2x2 wave grid, 64x64 each

    // XCD-bijective swizzle over 2048 blocks (nwg%8==0)
    const int bid = ((blockIdx.z << 5) + blockIdx.y) * 32 + blockIdx.x;  // 0..2047
    const int swz = ((bid & 7) << 8) + (bid >> 3);
    const int z = zbase + (swz >> 10), by = (swz >> 5) & 31, bx = swz & 31;

    const int row0 = by * 128, col0 = bx * 128;
    const short* Ag = (const short*)A + (size_t)z * NPIX * CH;
    const short* Bg = (const short*)Bm + (size_t)z * NPIX * CH;
    unsigned short* D = Dout + (size_t)z * NPIX * NPIX;

    const int srow = t >> 3;                        // 0..31 (staging row within round)
    const int kce  = ((t & 7) ^ (srow & 7)) * 8;    // pre-swizzled k offset within BK=64

    f32x4 acc[4][4] = {};

    // stage one BK=64 K-slab of A(128x64) + B(128x64): 4 rounds each, 8 loads/thread
#define STAGE_K(buf, k0)                                                                   \
    do {                                                                                   \
        _Pragma("unroll")                                                                  \
        for (int rr_ = 0; rr_ < 4; ++rr_)                                                  \
            gload_lds16(Ag + (size_t)(row0 + rr_ * 32 + srow) * KDIM + (k0) + kce,         \
                        &smem[ASOFF(buf) + rr_ * 2048 + wv * 512]);                        \
        _Pragma("unroll")                                                                  \
        for (int rr_ = 0; rr_ < 4; ++rr_)                                                  \
            gload_lds16(Bg + (size_t)(col0 + rr_ * 32 + srow) * KDIM + (k0) + kce,         \
                        &smem[BSOFF(buf) + rr_ * 2048 + wv * 512]);                        \
    } while (0)

    const int rsel = lane & 15, kq = lane >> 4;
    const int rx = rsel & 7;

#define CONSUME(buf)                                                                       \
    do {                                                                                   \
        _Pragma("unroll")                                                                  \
        for (int s = 0; s < 2; ++s) {                                                      \
            const int pk = (((s << 2) + kq) ^ rx) * 8;                                     \
            short8 a_[4], b_[4];                                                           \
            _Pragma("unroll")                                                              \
            for (int mi = 0; mi < 4; ++mi)                                                 \
                a_[mi] = *(const short8*)&smem[ASOFF(buf) + (wm * 64 + mi * 16 + rsel) * 64 + pk]; \
            _Pragma("unroll")                                                              \
            for (int ni = 0; ni < 4; ++ni)                                                 \
                b_[ni] = *(const short8*)&smem[BSOFF(buf) + (wn * 64 + ni * 16 + rsel) * 64 + pk]; \
            _Pragma("unroll")                                                              \
            for (int mi = 0; mi < 4; ++mi)                                                 \
                _Pragma("unroll")                                                          \
                for (int ni = 0; ni < 4; ++ni)                                             \
                    acc[mi][ni] = __builtin_amdgcn_mfma_f32_16x16x32_bf16(a_[mi], b_[ni],  \
                                                                          acc[mi][ni], 0, 0, 0); \
        }                                                                                  \
    } while (0)

    // K-iteration: counted vmcnt (8 loads/stage; next stage stays in flight across
    // both barriers). lgkmcnt(0) before bar2 = all ds_reads retired -> safe to
    // overwrite this buffer. STAGE after bar2 (prefetch distance 2).
#define KITER(it, VMC)                                              \
    do {                                                            \
        asm volatile("s_waitcnt vmcnt(" #VMC ")" ::: "memory");     \
        __builtin_amdgcn_sched_barrier(0);                          \
        __builtin_amdgcn_s_barrier();                               \
        __builtin_amdgcn_sched_barrier(0);                          \
        CONSUME((it) & 1);                                          \
        asm volatile("s_waitcnt lgkmcnt(0)" ::: "memory");          \
        __builtin_amdgcn_sched_barrier(0);                          \
        __builtin_amdgcn_s_barrier();                               \
        __builtin_amdgcn_sched_barrier(0);                          \
        if ((it) < 2) STAGE_K((it) & 1, ((it) + 2) * 64);           \
    } while (0)

    STAGE_K(0, 0);
    STAGE_K(1, 64);        // 16 loads in flight
    KITER(0, 8);
    KITER(1, 8);
    KITER(2, 8);
    KITER(3, 0);
#undef KITER
#undef CONSUME
#undef STAGE_K

    // ---- epilogue: stage C tile (128x128 bf16, 32 KB) in LDS, store dwordx4 ----
    // chunk-XOR swizzle: logical 8-short chunk ch of row r lives at ch^(r&15);
    // C/D layout: col = lane&15, row = (lane>>4)*4 + reg.
    const int rbase = (lane >> 4) * 4, cbase = lane & 15;
    unsigned short* Cs = (unsigned short*)smem;
#pragma unroll
    for (int mi = 0; mi < 4; ++mi)
#pragma unroll
        for (int ni = 0; ni < 4; ++ni) {
            int c = wn * 64 + ni * 16 + cbase;
#pragma unroll
            for (int r = 0; r < 4; ++r) {
                int row = wm * 64 + mi * 16 + rbase + r;
                int pc = (((c >> 3) ^ (row & 15)) * 8) + (c & 7);
                Cs[row * 128 + pc] = f32_to_bf16(acc[mi][ni][r]);
            }
        }
    __syncthreads();
#pragma unroll
    for (int rd = 0; rd < 8; ++rd) {
        int rr = rd * 16 + (t >> 4);
        int pc = ((t & 15) ^ (rr & 15)) * 8;
        uint4 v = *(const uint4*)&Cs[rr * 128 + pc];
        *(uint4*)&D[(size_t)(row0 + rr) * NPIX + col0 + (t & 15) * 8] = v;
    }
#undef ASOFF
#undef BSOFF
}

__device__ __forceinline__ void load_tile16(const unsigned short* __restrict__ D,
                                            int row, int col, float* f) {
    const unsigned short* rp = D + (size_t)row * NPIX + col;
    uint4 u0 = *(const uint4*)rp;
    uint4 u1 = *(const uint4*)(rp + 8);
    const unsigned* w0 = (const unsigned*)&u0;
    const unsigned* w1 = (const unsigned*)&u1;
#pragma unroll
    for (int w = 0; w < 4; ++w) {
        f[2 * w]         = bf16_to_f32((unsigned short)w0[w]);
        f[2 * w + 1]     = bf16_to_f32((unsigned short)(w0[w] >> 16));
        f[8 + 2 * w]     = bf16_to_f32((unsigned short)w1[w]);
        f[8 + 2 * w + 1] = bf16_to_f32((unsigned short)(w1[w] >> 16));
    }
}

// ---- K3 (k_score): rolling diagonal segments, SEG=8.
// R5: same thread mapping / arithmetic / sum order as the 46.2us R3 version
// (R4's DPP rewrite regressed: kernel is LATENCY-bound, not LDS-bound).
// Schedule changes only:
//  * V double-buffered (V[k&1]) -> ONE barrier per step (was 2). Write(k+2)
//    vs read(k) hazard ordered by the two intervening barriers (each
//    __syncthreads drains lgkm before release).
//  * C-tile prefetch: prologue loads tiles 0,1,2; loop issues tile k+3 right
//    after the barrier so its HBM/L2 latency hides under the score phase
//    instead of stalling v = A+B+C.
__global__ __launch_bounds__(256) void k_score(const unsigned short* __restrict__ Dbase,
                                               unsigned long long* __restrict__ keys) {
    const int z = blockIdx.z;
    const unsigned short* D = Dbase + (size_t)z * NPIX * NPIX;
    const int t = threadIdx.x;

    const int d = (int)blockIdx.x - 61;            // diagonal qr-pr in [-61, 61]
    const int adg = d < 0 ? -d : d;
    const int len = 62 - adg;
    const int s0 = blockIdx.y * SEG;
    if (s0 >= len) return;
    const int steps = min(SEG, len - s0);
    const int qr0 = (d > 0 ? d : 0) + s0;
    const int pr0 = qr0 - d;

    __shared__ __align__(16) float V[2][64 * VROW];   // 2 x 17408 B -> 4 blocks/CU

    const int a = t >> 2, b0 = (t & 3) * 16;
    const int g = t >> 6, qc = t & 63;
    const int qcr = qc < OH ? qc : (OH - 1);
    const int pc0 = g * 16;
    const int kmax = (g == 3) ? 14 : 16;

    float A[16], B[16], C[16];
    load_tile16(D, (qr0 + 0) * 64 + a, (pr0 + 0) * 64 + b0, A);
    load_tile16(D, (qr0 + 1) * 64 + a, (pr0 + 1) * 64 + b0, B);
    load_tile16(D, (qr0 + 2) * 64 + a, (pr0 + 2) * 64 + b0, C);

    for (int k = 0; k < steps; ++k) {
        float* Vb = V[k & 1];
        float v[16];
#pragma unroll
        for (int e = 0; e < 16; ++e) v[e] = A[e] + B[e] + C[e];
#pragma unroll
        for (int e = 0; e < 16; e += 4)
            *(f32x4*)&Vb[a * VROW + b0 + e] = *(const f32x4*)&v[e];
        __syncthreads();                           // Vb ready; prev buffer now free

        // shift window + issue next C load (latency hides under score phase)
#pragma unroll
        for (int e = 0; e < 16; ++e) { A[e] = B[e]; B[e] = C[e]; }
        if (k + 1 < steps)
            load_tile16(D, (qr0 + k + 3) * 64 + a, (pr0 + k + 3) * 64 + b0, C);

        float r0[16], r1[20], r2[20];
#pragma unroll
        for (int e = 0; e < 16; e += 4)
            *(f32x4*)&r0[e] = *(const f32x4*)&Vb[qcr * VROW + pc0 + e];
#pragma unroll
        for (int e = 0; e < 20; e += 4)
            *(f32x4*)&r1[e] = *(const f32x4*)&Vb[(qcr + 1) * VROW + pc0 + e];
#pragma unroll
        for (int e = 0; e < 20; e += 4)
            *(f32x4*)&r2[e] = *(const f32x4*)&Vb[(qcr + 2) * VROW + pc0 + e];
        float best = -1e30f; int bpc = 0;
#pragma unroll
        for (int kk = 0; kk < 16; ++kk) {
            float s = r0[kk] + r1[kk + 1] + r2[kk + 2];
            if (kk < kmax && s > best) { best = s; bpc = pc0 + kk; }
        }
        if (qc < OH) {
            unsigned u = __float_as_uint(best);
            u = (best >= 0.f) ? (u | 0x80000000u) : ~u;
            unsigned long long key = ((unsigned long long)u << 12)
                                   | (unsigned)((63 - (pr0 + k)) << 6)
                                   | (unsigned)(63 - bpc);
            atomicMax(&keys[(size_t)z * NPATCH + (qr0 + k) * OH + qc], key);
        }
    }
}

// -------- K4 (k_loss): decode keys -> match; loss via norm expansion --------
__global__ void k_loss(const unsigned short* __restrict__ Dbase,
                       const unsigned long long* __restrict__ keys,
                       const float* __restrict__ ssPb, const float* __restrict__ invPb,
                       const float* __restrict__ ssTb, const float* __restrict__ invTb,
                       float* __restrict__ out) {
    const int z = blockIdx.y;
    const unsigned short* D = Dbase + (size_t)z * NPIX * NPIX;
    const float* ssP  = ssPb  + z * NPIX;
    const float* invP = invPb + z * NPIX;
    const float* ssT  = ssTb  + z * NPIX;
    const float* invT = invTb + z * NPIX;
    int q = blockIdx.x * 256 + threadIdx.x;
    float acc = 0.f;
    if (q < NPATCH) {
        int qr = q / OH, qc = q - qr * OH;
        int qpix = qr * WW + qc;
        unsigned long long key = keys[(size_t)z * NPATCH + q];
        int mpr = 63 - (int)((key >> 6) & 63);
        int mpc = 63 - (int)(key & 63);
        int mpix = mpr * WW + mpc;
#pragma unroll
        for (int i = 0; i < 3; ++i)
#pragma unroll
            for (int j = 0; j < 3; ++j) {
                int off = i * WW + j;
                int y = qpix + off, x = mpix + off;
                float Dv = bf16_to_f32(D[(size_t)y * NPIX + x]);
                float nP = ssP[y] * invP[y];       // = ||p_y||
                float nT = ssT[x] * invT[x];
                acc += ssP[y] + ssT[x] - 2.f * Dv * nP * nT;
            }
    }
#pragma unroll
    for (int s = 32; s > 0; s >>= 1) acc += __shfl_down(acc, s, 64);
    if ((threadIdx.x & 63) == 0)
        atomicAdd(out, acc * (1.f / 35426304.f));  // / (4*3844*2304)
}

// ---------------------------------- launch ----------------------------------
extern "C" void kernel_launch(void* const* d_in, const int* in_sizes, int n_in,
                              void* d_out, int out_size, void* d_ws, size_t ws_size,
                              hipStream_t stream) {
    const float* pred = (const float*)d_in[0];
    const float* tgt  = (const float*)d_in[1];
    char* ws = (char*)d_ws;
    // ws layout (bytes), ws_size = 256 MiB:
    // D(bf16, 4 batches) 128MB | Xn 8MB | Tn 8MB | norms 4x64KB | keys 123KB
    unsigned short*     Dws  = (unsigned short*)(ws);
    __hip_bfloat16*     Xn   = (__hip_bfloat16*)(ws + 134217728);
    __hip_bfloat16*     Tn   = (__hip_bfloat16*)(ws + 142606336);
    float*              ssP  = (float*)(ws + 150994944);
    float*              invP = (float*)(ws + 151060480);
    float*              ssT  = (float*)(ws + 151126016);
    float*              invT = (float*)(ws + 151191552);
    unsigned long long* keys = (unsigned long long*)(ws + 151257088);

    k_prep<<<dim3(64, 8), 256, 0, stream>>>(pred, tgt, Xn, Tn, ssP, invP, ssT, invT,
                                            keys, (float*)d_out);
    k_gemm<<<dim3(32, 32, 2), 256, 0, stream>>>(Xn, Tn, Dws, 0);
    k_gemm<<<dim3(32, 32, 2), 256, 0, stream>>>(Xn, Tn, Dws, 2);
    k_score<<<dim3(123, 8, 4), 256, 0, stream>>>(Dws, keys);
    k_loss<<<dim3(16, 4), 256, 0, stream>>>(Dws, keys, ssP, invP, ssT, invT,
                                            (float*)d_out);
}

// Round 6
// 179.912 us; speedup vs baseline: 1.1043x; 1.0217x over previous
//
#include <hip/hip_runtime.h>
#include <hip/hip_bf16.h>

#define NB 4
#define CH 256
#define HH 64
#define WW 64
#define NPIX 4096      // HH*WW
#define OH 62
#define NPATCH 3844    // 62*62
#define KDIM 256       // == CH
#define EPSN 1e-12f
#define SEG 8          // diagonal segment length (row-pairs per block)
#define PST 68         // k_prep stage row stride (shorts): 8B-aligned rows

typedef __attribute__((ext_vector_type(8))) short short8;
typedef __attribute__((ext_vector_type(4))) float f32x4;

__device__ __forceinline__ float bf16_to_f32(unsigned short u) {
    return __uint_as_float((unsigned)u << 16);
}
__device__ __forceinline__ unsigned short f32_to_bf16(float f) {
    __hip_bfloat16 h = __float2bfloat16(f);
    return *(unsigned short*)&h;
}

// ---- K1 (fused prep): read inputs ONCE; per-pixel ss + inv-norm; normalized bf16
// ---- transpose (C,pix)->(pix,C). Also zero-inits d_out + keys.
__global__ __launch_bounds__(256) void k_prep(const float* __restrict__ pred,
                                              const float* __restrict__ tgt,
                                              __hip_bfloat16* __restrict__ Xn,
                                              __hip_bfloat16* __restrict__ Tn,
                                              float* __restrict__ ssP, float* __restrict__ invP,
                                              float* __restrict__ ssT, float* __restrict__ invT,
                                              unsigned long long* __restrict__ keys,
                                              float* __restrict__ out) {
    const int bz = blockIdx.y;            // 0..7
    const int b = bz >> 1, which = bz & 1;
    const float* src = (which ? tgt : pred) + (size_t)b * CH * NPIX;
    unsigned short* dst = (unsigned short*)((which ? Tn : Xn) + (size_t)b * NPIX * CH);
    float* ss_g  = (which ? ssT  : ssP)  + b * NPIX;
    float* inv_g = (which ? invT : invP) + b * NPIX;
    const int pix0 = blockIdx.x * 64;
    const int t = threadIdx.x, lane = t & 63, wv = t >> 6;

    int gid = (bz * 64 + blockIdx.x) * 256 + t;
    if (gid < NB * NPATCH) keys[gid] = 0ull;
    if (gid == 0) out[0] = 0.f;

    __shared__ unsigned short stage[CH][PST];  // 34816 B
    __shared__ float partial[16][68];          // 4352 B (+pad: 2-way reads)
    __shared__ float inv_s[64];

    // load: thread (cb = t>>4, ch = t&15) covers c = cb*16+r (r<16), pixels ch*4..+3
    const int cb = t >> 4, chk = t & 15;
    float ss0 = 0.f, ss1 = 0.f, ss2 = 0.f, ss3 = 0.f;
#pragma unroll
    for (int r = 0; r < 16; ++r) {
        int c = cb * 16 + r;
        float4 v = *(const float4*)&src[(size_t)c * NPIX + pix0 + chk * 4];
        ss0 += v.x * v.x; ss1 += v.y * v.y; ss2 += v.z * v.z; ss3 += v.w * v.w;
        ushort4 sv;
        sv.x = f32_to_bf16(v.x); sv.y = f32_to_bf16(v.y);
        sv.z = f32_to_bf16(v.z); sv.w = f32_to_bf16(v.w);
        *(ushort4*)&stage[c][chk * 4] = sv;
    }
    float4 pv; pv.x = ss0; pv.y = ss1; pv.z = ss2; pv.w = ss3;
    *(float4*)&partial[cb][chk * 4] = pv;
    __syncthreads();
    if (t < 64) {
        float ss = 0.f;
#pragma unroll
        for (int r = 0; r < 16; ++r) ss += partial[r][t];
        float inv = 1.f / fmaxf(sqrtf(ss), EPSN);
        ss_g[pix0 + t] = ss;
        inv_g[pix0 + t] = inv;
        inv_s[t] = inv;
    }
    __syncthreads();
    // write: pixel p (16/wave), lane = c within 64-chunk; 2-way-free LDS reads
    for (int p = wv; p < 64; p += 4) {
        float iv = inv_s[p];
#pragma unroll
        for (int cc = 0; cc < 4; ++cc) {
            int c = cc * 64 + lane;
            float v = bf16_to_f32(stage[c][p]) * iv;
            dst[(size_t)(pix0 + p) * CH + c] = f32_to_bf16(v);
        }
    }
}

// ------- K2: D = Xn * Tn^T (4096x4096, K=256, bf16 MFMA, bf16 OUTPUT).
// LOCKED R1/R3 config (57.3 us combined, three independent measurements;
// R2/R4 reshapes failed). Split into two z-dispatches for rocprof visibility.
__device__ __forceinline__ void gload_lds16(const void* g, void* l) {
    __builtin_amdgcn_global_load_lds(
        (const __attribute__((address_space(1))) void*)g,
        (__attribute__((address_space(3))) void*)l, 16, 0, 0);
}

__global__ __launch_bounds__(256, 2) void k_gemm(const __hip_bfloat16* __restrict__ A,
                                                 const __hip_bfloat16* __restrict__ Bm,
                                                 unsigned short* __restrict__ Dout,
                                                 int zbase) {
    // one 64 KB arena: As buf0 [0,8192), As buf1 [8192,16384),
    //                  Bs buf0 [16384,24576), Bs buf1 [24576,32768) (shorts)
    __shared__ __align__(16) short smem[32768];
#define ASOFF(buf) ((buf) * 8192)
#define BSOFF(buf) (16384 + (buf) * 8192)

    const int t = threadIdx.x;
    const int lane = t & 63, wv = t >> 6;          // 4 waves
    const int wm = wv >> 1, wn = wv & 1;           // 2x2 wave grid, 64x64 each

    // XCD-bijective swizzle over 2048 blocks (nwg%8==0)
    const int bid = ((blockIdx.z << 5) + blockIdx.y) * 32 + blockIdx.x;  // 0..2047
    const int swz = ((bid & 7) << 8) + (bid >> 3);
    const int z = zbase + (swz >> 10), by = (swz >> 5) & 31, bx = swz & 31;

    const int row0 = by * 128, col0 = bx * 128;
    const short* Ag = (const short*)A + (size_t)z * NPIX * CH;
    const short* Bg = (const short*)Bm + (size_t)z * NPIX * CH;
    unsigned short* D = Dout + (size_t)z * NPIX * NPIX;

    const int srow = t >> 3;                        // 0..31 (staging row within round)
    const int kce  = ((t & 7) ^ (srow & 7)) * 8;    // pre-swizzled k offset within BK=64

    f32x4 acc[4][4] = {};

    // stage one BK=64 K-slab of A(128x64) + B(128x64): 4 rounds each, 8 loads/thread
#define STAGE_K(buf, k0)                                                                   \
    do {                                                                                   \
        _Pragma("unroll")                                                                  \
        for (int rr_ = 0; rr_ < 4; ++rr_)                                                  \
            gload_lds16(Ag + (size_t)(row0 + rr_ * 32 + srow) * KDIM + (k0) + kce,         \
                        &smem[ASOFF(buf) + rr_ * 2048 + wv * 512]);                        \
        _Pragma("unroll")                                                                  \
        for (int rr_ = 0; rr_ < 4; ++rr_)                                                  \
            gload_lds16(Bg + (size_t)(col0 + rr_ * 32 + srow) * KDIM + (k0) + kce,         \
                        &smem[BSOFF(buf) + rr_ * 2048 + wv * 512]);                        \
    } while (0)

    const int rsel = lane & 15, kq = lane >> 4;
    const int rx = rsel & 7;

#define CONSUME(buf)                                                                       \
    do {                                                                                   \
        _Pragma("unroll")                                                                  \
        for (int s = 0; s < 2; ++s) {                                                      \
            const int pk = (((s << 2) + kq) ^ rx) * 8;                                     \
            short8 a_[4], b_[4];                                                           \
            _Pragma("unroll")                                                              \
            for (int mi = 0; mi < 4; ++mi)                                                 \
                a_[mi] = *(const short8*)&smem[ASOFF(buf) + (wm * 64 + mi * 16 + rsel) * 64 + pk]; \
            _Pragma("unroll")                                                              \
            for (int ni = 0; ni < 4; ++ni)                                                 \
                b_[ni] = *(const short8*)&smem[BSOFF(buf) + (wn * 64 + ni * 16 + rsel) * 64 + pk]; \
            _Pragma("unroll")                                                              \
            for (int mi = 0; mi < 4; ++mi)                                                 \
                _Pragma("unroll")                                                          \
                for (int ni = 0; ni < 4; ++ni)                                             \
                    acc[mi][ni] = __builtin_amdgcn_mfma_f32_16x16x32_bf16(a_[mi], b_[ni],  \
                                                                          acc[mi][ni], 0, 0, 0); \
        }                                                                                  \
    } while (0)

#define KITER(it, VMC)                                              \
    do {                                                            \
        asm volatile("s_waitcnt vmcnt(" #VMC ")" ::: "memory");     \
        __builtin_amdgcn_sched_barrier(0);                          \
        __builtin_amdgcn_s_barrier();                               \
        __builtin_amdgcn_sched_barrier(0);                          \
        CONSUME((it) & 1);                                          \
        asm volatile("s_waitcnt lgkmcnt(0)" ::: "memory");          \
        __builtin_amdgcn_sched_barrier(0);                          \
        __builtin_amdgcn_s_barrier();                               \
        __builtin_amdgcn_sched_barrier(0);                          \
        if ((it) < 2) STAGE_K((it) & 1, ((it) + 2) * 64);           \
    } while (0)

    STAGE_K(0, 0);
    STAGE_K(1, 64);        // 16 loads in flight
    KITER(0, 8);
    KITER(1, 8);
    KITER(2, 8);
    KITER(3, 0);
#undef KITER
#undef CONSUME
#undef STAGE_K

    // ---- epilogue: stage C tile (128x128 bf16, 32 KB) in LDS, store dwordx4 ----
    const int rbase = (lane >> 4) * 4, cbase = lane & 15;
    unsigned short* Cs = (unsigned short*)smem;
#pragma unroll
    for (int mi = 0; mi < 4; ++mi)
#pragma unroll
        for (int ni = 0; ni < 4; ++ni) {
            int c = wn * 64 + ni * 16 + cbase;
#pragma unroll
            for (int r = 0; r < 4; ++r) {
                int row = wm * 64 + mi * 16 + rbase + r;
                int pc = (((c >> 3) ^ (row & 15)) * 8) + (c & 7);
                Cs[row * 128 + pc] = f32_to_bf16(acc[mi][ni][r]);
            }
        }
    __syncthreads();
#pragma unroll
    for (int rd = 0; rd < 8; ++rd) {
        int rr = rd * 16 + (t >> 4);
        int pc = ((t & 15) ^ (rr & 15)) * 8;
        uint4 v = *(const uint4*)&Cs[rr * 128 + pc];
        *(uint4*)&D[(size_t)(row0 + rr) * NPIX + col0 + (t & 15) * 8] = v;
    }
#undef ASOFF
#undef BSOFF
}

// ---- K3 (k_score) R6: barrier-free, LDS-free streaming formulation.
// score(qc,pc) = sum_i sum_j D[(qr+i)64+qc+j][(pr+i)64+pc+j].
// Sum j FIRST inside each tile: G[a][b] = T[a][b]+T[a+1][b+1]+T[a+2][b+2]
// (intra-tile: qc+j<=63, pc+j<=63 always). Then score = GA+GB+GC ELEMENTWISE at
// the same (a,b) -> rolling register tiles, no thread remap, no LDS, no barriers.
// Thread (a = t>>2, colgroup = t&3): loads rows a,a+1,a+2 cols [b0,b0+17] (L1-hot,
// neighbors load the same rows), computes G locally, per-thread argmax over its
// 16 pc, 2x shfl_xor reduce across the 4 col-groups, ONE atomicMax per (q,step)
// from lane gcol==0 (62/step vs 248/step before: WRITE 30.7 -> ~8 MB).
// FP order: (A0+A1+A2)+(B..)+(C..) vs old (A0+B0+C0)+...: ~1ulp f32 reorder,
// far below the bf16-D perturbation the argmax already tolerates.
__device__ __forceinline__ void load_row18(const unsigned short* __restrict__ rp,
                                           bool full, float* o) {
    uint4 u0 = *(const uint4*)rp;          // cols 0..7
    uint4 u1 = *(const uint4*)(rp + 8);    // cols 8..15
    unsigned e = full ? *(const unsigned*)(rp + 16) : 0u;  // cols 16,17
    const unsigned* w0 = (const unsigned*)&u0;
    const unsigned* w1 = (const unsigned*)&u1;
#pragma unroll
    for (int w = 0; w < 4; ++w) {
        o[2 * w]         = bf16_to_f32((unsigned short)w0[w]);
        o[2 * w + 1]     = bf16_to_f32((unsigned short)(w0[w] >> 16));
        o[8 + 2 * w]     = bf16_to_f32((unsigned short)w1[w]);
        o[8 + 2 * w + 1] = bf16_to_f32((unsigned short)(w1[w] >> 16));
    }
    o[16] = bf16_to_f32((unsigned short)e);
    o[17] = bf16_to_f32((unsigned short)(e >> 16));
}

__device__ __forceinline__ void gtile(const unsigned short* __restrict__ D,
                                      int tr, int tc, int a, int b0, bool full,
                                      float* G) {
    const unsigned short* base = D + (size_t)(tr * 64 + a) * NPIX + tc * 64 + b0;
    float r0[18], r1[18], r2[18];
    load_row18(base, full, r0);
    load_row18(base + NPIX, full, r1);
    load_row18(base + 2 * NPIX, full, r2);
#pragma unroll
    for (int kk = 0; kk < 16; ++kk)
        G[kk] = r0[kk] + r1[kk + 1] + r2[kk + 2];
}

__global__ __launch_bounds__(256) void k_score(const unsigned short* __restrict__ Dbase,
                                               unsigned long long* __restrict__ keys) {
    const int z = blockIdx.z;
    const unsigned short* D = Dbase + (size_t)z * NPIX * NPIX;
    const int t = threadIdx.x;

    const int d = (int)blockIdx.x - 61;            // diagonal qr-pr in [-61, 61]
    const int adg = d < 0 ? -d : d;
    const int len = 62 - adg;
    const int s0 = blockIdx.y * SEG;
    if (s0 >= len) return;
    const int steps = min(SEG, len - s0);
    const int qr0 = (d > 0 ? d : 0) + s0;
    const int pr0 = qr0 - d;

    const int a = t >> 2;                          // tile row = qc, 0..63
    const int gcol = t & 3;
    const int b0 = gcol * 16;
    const int kmax = (gcol == 3) ? 14 : 16;        // pc <= 61
    const bool full = (gcol < 3);                  // needs cols b0+16,b0+17
    const bool act = (a < OH);                     // qc <= 61 scores; 62,63 idle

    float G0[16], G1[16], G2[16];
    if (act) {
        gtile(D, qr0 + 0, pr0 + 0, a, b0, full, G0);
        gtile(D, qr0 + 1, pr0 + 1, a, b0, full, G1);
    }

#define SCORE_STEP(K, GA, GB, GC)                                                 \
    if ((K) < steps) {                                                            \
        if (act) gtile(D, qr0 + (K) + 2, pr0 + (K) + 2, a, b0, full, GC);         \
        float best = -1e30f; int bpc = 0;                                         \
        _Pragma("unroll")                                                         \
        for (int kk = 0; kk < 16; ++kk) {                                         \
            float s = GA[kk] + GB[kk] + GC[kk];                                   \
            if (kk < kmax && s > best) { best = s; bpc = b0 + kk; }               \
        }                                                                         \
        float os_; int opc_;                                                      \
        os_ = __shfl_xor(best, 1, 64); opc_ = __shfl_xor(bpc, 1, 64);             \
        if (os_ > best || (os_ == best && opc_ < bpc)) { best = os_; bpc = opc_; }\
        os_ = __shfl_xor(best, 2, 64); opc_ = __shfl_xor(bpc, 2, 64);             \
        if (os_ > best || (os_ == best && opc_ < bpc)) { best = os_; bpc = opc_; }\
        if (act && gcol == 0) {                                                   \
            unsigned u = __float_as_uint(best);                                   \
            u = (best >= 0.f) ? (u | 0x80000000u) : ~u;                           \
            unsigned long long key = ((unsigned long long)u << 12)                \
                                   | (unsigned)((63 - (pr0 + (K))) << 6)          \
                                   | (unsigned)(63 - bpc);                        \
            atomicMax(&keys[(size_t)z * NPATCH + (qr0 + (K)) * OH + a], key);     \
        }                                                                         \
    }

    SCORE_STEP(0, G0, G1, G2)
    SCORE_STEP(1, G1, G2, G0)
    SCORE_STEP(2, G2, G0, G1)
    SCORE_STEP(3, G0, G1, G2)
    SCORE_STEP(4, G1, G2, G0)
    SCORE_STEP(5, G2, G0, G1)
    SCORE_STEP(6, G0, G1, G2)
    SCORE_STEP(7, G1, G2, G0)
#undef SCORE_STEP
}

// -------- K4 (k_loss): decode keys -> match; loss via norm expansion --------
__global__ void k_loss(const unsigned short* __restrict__ Dbase,
                       const unsigned long long* __restrict__ keys,
                       const float* __restrict__ ssPb, const float* __restrict__ invPb,
                       const float* __restrict__ ssTb, const float* __restrict__ invTb,
                       float* __restrict__ out) {
    const int z = blockIdx.y;
    const unsigned short* D = Dbase + (size_t)z * NPIX * NPIX;
    const float* ssP  = ssPb  + z * NPIX;
    const float* invP = invPb + z * NPIX;
    const float* ssT  = ssTb  + z * NPIX;
    const float* invT = invTb + z * NPIX;
    int q = blockIdx.x * 256 + threadIdx.x;
    float acc = 0.f;
    if (q < NPATCH) {
        int qr = q / OH, qc = q - qr * OH;
        int qpix = qr * WW + qc;
        unsigned long long key = keys[(size_t)z * NPATCH + q];
        int mpr = 63 - (int)((key >> 6) & 63);
        int mpc = 63 - (int)(key & 63);
        int mpix = mpr * WW + mpc;
#pragma unroll
        for (int i = 0; i < 3; ++i)
#pragma unroll
            for (int j = 0; j < 3; ++j) {
                int off = i * WW + j;
                int y = qpix + off, x = mpix + off;
                float Dv = bf16_to_f32(D[(size_t)y * NPIX + x]);
                float nP = ssP[y] * invP[y];       // = ||p_y||
                float nT = ssT[x] * invT[x];
                acc += ssP[y] + ssT[x] - 2.f * Dv * nP * nT;
            }
    }
#pragma unroll
    for (int s = 32; s > 0; s >>= 1) acc += __shfl_down(acc, s, 64);
    if ((threadIdx.x & 63) == 0)
        atomicAdd(out, acc * (1.f / 35426304.f));  // / (4*3844*2304)
}

// ---------------------------------- launch ----------------------------------
extern "C" void kernel_launch(void* const* d_in, const int* in_sizes, int n_in,
                              void* d_out, int out_size, void* d_ws, size_t ws_size,
                              hipStream_t stream) {
    const float* pred = (const float*)d_in[0];
    const float* tgt  = (const float*)d_in[1];
    char* ws = (char*)d_ws;
    // ws layout (bytes), ws_size = 256 MiB:
    // D(bf16, 4 batches) 128MB | Xn 8MB | Tn 8MB | norms 4x64KB | keys 123KB
    unsigned short*     Dws  = (unsigned short*)(ws);
    __hip_bfloat16*     Xn   = (__hip_bfloat16*)(ws + 134217728);
    __hip_bfloat16*     Tn   = (__hip_bfloat16*)(ws + 142606336);
    float*              ssP  = (float*)(ws + 150994944);
    float*              invP = (float*)(ws + 151060480);
    float*              ssT  = (float*)(ws + 151126016);
    float*              invT = (float*)(ws + 151191552);
    unsigned long long* keys = (unsigned long long*)(ws + 151257088);

    k_prep<<<dim3(64, 8), 256, 0, stream>>>(pred, tgt, Xn, Tn, ssP, invP, ssT, invT,
                                            keys, (float*)d_out);
    k_gemm<<<dim3(32, 32, 2), 256, 0, stream>>>(Xn, Tn, Dws, 0);
    k_gemm<<<dim3(32, 32, 2), 256, 0, stream>>>(Xn, Tn, Dws, 2);
    k_score<<<dim3(123, 8, 4), 256, 0, stream>>>(Dws, keys);
    k_loss<<<dim3(16, 4), 256, 0, stream>>>(Dws, keys, ssP, invP, ssT, invT,
                                            (float*)d_out);
}